// Round 2
// baseline (919.871 us; speedup 1.0000x reference)
//
#include <hip/hip_runtime.h>
#include <cstdint>
#include <cstdio>

// ---------------- problem constants ----------------
#define B_SZ    4096
#define WID     4096       // (nrx ntx user) = 16*32*8
#define HW2     8192       // 2 * WID
#define NELEM   33554432.0 // B*2*WID, BN population
#define NFEAT   3072
#define KDIM    8192
#define NV      2048

typedef _Float16 f16x8 __attribute__((ext_vector_type(8)));
typedef _Float16 f16x4 __attribute__((ext_vector_type(4)));
typedef float    f32x4 __attribute__((ext_vector_type(4)));

// global_load_lds, 16B per lane. LDS dest = wave-uniform base + lane*16.
__device__ __forceinline__ void gld_lds16(const void* g, void* l) {
  __builtin_amdgcn_global_load_lds(
      (const __attribute__((address_space(1))) unsigned int*)(uintptr_t)g,
      (__attribute__((address_space(3))) unsigned int*)(uintptr_t)l,
      16, 0, 0);
}

__device__ __forceinline__ float elu_aff(float x, float a, float b) {
  float z = fmaf(a, x, b);
  return z > 0.f ? z : expm1f(z);
}

// ---------------- conv + BN-stat kernel (register-resident, no big LDS) ----
// One block (512 thr) per batch element. Thread t owns w in [t*8, t*8+8) for
// BOTH image rows; conv inputs live in registers; halo values cross threads
// via tiny stride-1 LDS arrays (conflict-free). Emits per-block sum/sumsq of
// the conv output (pre-BN), matching reference BN-over-batch stats.
template<bool FIRST>
__global__ __launch_bounds__(512) void conv_bn_kernel(
    const float* __restrict__ in, float* __restrict__ outc,
    const float* __restrict__ cw9, const float* __restrict__ cb,
    const float2* __restrict__ param_prev,   // (a,b) of previous BN+ELU input map
    float2* __restrict__ partial)            // [4096] per-block (sum, sumsq)
{
  __shared__ float bL0[512], bL1[512], bR0[512], bR1[512];
  __shared__ float red[16];
  const int t = threadIdx.x;
  const int b = blockIdx.x;
  const float* __restrict__ src = in + (size_t)b * HW2;
  const int s = t * 8;

  float e0[8], e1[8];   // conv input h, row0/row1, this thread's 8 columns
  if constexpr (FIRST) {
    // x[b] linear: li = k*1024 + nrx*64 + ntx*2 + c ; h[c][w], w = nrx*256+ntx*8+k
    // thread owns fixed (nrx,ntx), k = 0..7
    const int nrx = t >> 5, ntx = t & 31;
    const float* __restrict__ base = src + nrx * 64 + ntx * 2;
    #pragma unroll
    for (int k = 0; k < 8; ++k) {
      const float2 p = *(const float2*)(base + k * 1024);
      e0[k] = p.x; e1[k] = p.y;
    }
  } else {
    const float a_aff = param_prev->x, b_aff = param_prev->y;
    const float4 v0 = *(const float4*)(src + s);
    const float4 v1 = *(const float4*)(src + s + 4);
    const float4 u0 = *(const float4*)(src + WID + s);
    const float4 u1 = *(const float4*)(src + WID + s + 4);
    e0[0]=elu_aff(v0.x,a_aff,b_aff); e0[1]=elu_aff(v0.y,a_aff,b_aff);
    e0[2]=elu_aff(v0.z,a_aff,b_aff); e0[3]=elu_aff(v0.w,a_aff,b_aff);
    e0[4]=elu_aff(v1.x,a_aff,b_aff); e0[5]=elu_aff(v1.y,a_aff,b_aff);
    e0[6]=elu_aff(v1.z,a_aff,b_aff); e0[7]=elu_aff(v1.w,a_aff,b_aff);
    e1[0]=elu_aff(u0.x,a_aff,b_aff); e1[1]=elu_aff(u0.y,a_aff,b_aff);
    e1[2]=elu_aff(u0.z,a_aff,b_aff); e1[3]=elu_aff(u0.w,a_aff,b_aff);
    e1[4]=elu_aff(u1.x,a_aff,b_aff); e1[5]=elu_aff(u1.y,a_aff,b_aff);
    e1[6]=elu_aff(u1.z,a_aff,b_aff); e1[7]=elu_aff(u1.w,a_aff,b_aff);
  }

  bL0[t] = e0[0]; bL1[t] = e1[0]; bR0[t] = e0[7]; bR1[t] = e1[7];
  __syncthreads();
  const float h0m0 = (t > 0)   ? bR0[t - 1] : 0.f;   // h[0][s-1]
  const float h1m0 = (t > 0)   ? bR1[t - 1] : 0.f;
  const float h0p8 = (t < 511) ? bL0[t + 1] : 0.f;   // h[0][s+8]
  const float h1p8 = (t < 511) ? bL1[t + 1] : 0.f;

  const float w00=cw9[0],w01=cw9[1],w02=cw9[2],
              w10=cw9[3],w11=cw9[4],w12=cw9[5],
              w20=cw9[6],w21=cw9[7],w22=cw9[8];
  const float bias = cb[0];

  float r0[8], r1[8];
  float lsum = 0.f, lss = 0.f;
  float h0m = h0m0, h1m = h1m0;
  #pragma unroll
  for (int e = 0; e < 8; ++e) {
    const float h0c = e0[e], h1c = e1[e];
    const float h0p = (e < 7) ? e0[e + 1] : h0p8;
    const float h1p = (e < 7) ? e1[e + 1] : h1p8;
    // SAME pad, H=2: out row0 = w[1]·row0 + w[2]·row1 ; out row1 = w[0]·row0 + w[1]·row1
    const float a0 = bias + w10*h0m + w11*h0c + w12*h0p + w20*h1m + w21*h1c + w22*h1p;
    const float a1 = bias + w00*h0m + w01*h0c + w02*h0p + w10*h1m + w11*h1c + w12*h1p;
    r0[e] = a0; r1[e] = a1;
    lsum += a0 + a1;
    lss  += a0*a0 + a1*a1;
    h0m = h0c; h1m = h1c;
  }

  float* __restrict__ dst = outc + (size_t)b * HW2;
  *(float4*)(dst + s)           = make_float4(r0[0], r0[1], r0[2], r0[3]);
  *(float4*)(dst + s + 4)       = make_float4(r0[4], r0[5], r0[6], r0[7]);
  *(float4*)(dst + WID + s)     = make_float4(r1[0], r1[1], r1[2], r1[3]);
  *(float4*)(dst + WID + s + 4) = make_float4(r1[4], r1[5], r1[6], r1[7]);

  // block reduce: 8 waves
  #pragma unroll
  for (int m = 1; m < 64; m <<= 1) {
    lsum += __shfl_xor(lsum, m, 64);
    lss  += __shfl_xor(lss,  m, 64);
  }
  const int wv = t >> 6;
  if ((t & 63) == 0) { red[wv] = lsum; red[8 + wv] = lss; }
  __syncthreads();
  if (t == 0) {
    float S = 0.f, SS = 0.f;
    #pragma unroll
    for (int i = 0; i < 8; ++i) { S += red[i]; SS += red[8 + i]; }
    partial[b] = make_float2(S, SS);
  }
}

// ---------------- stats -> affine params ----------------
__global__ void stat_reduce_kernel(const float2* __restrict__ part,
                                   const float* __restrict__ g,
                                   const float* __restrict__ be,
                                   float2* __restrict__ pout)
{
  const int t = threadIdx.x;
  double s = 0.0, ss = 0.0;
  for (int i = t; i < B_SZ; i += 256) {
    const float2 p = part[i];
    s += (double)p.x; ss += (double)p.y;
  }
  #pragma unroll
  for (int m = 1; m < 64; m <<= 1) {
    s  += __shfl_xor(s,  m, 64);
    ss += __shfl_xor(ss, m, 64);
  }
  __shared__ double rs[4], rss[4];
  const int wv = t >> 6;
  if ((t & 63) == 0) { rs[wv] = s; rss[wv] = ss; }
  __syncthreads();
  if (t == 0) {
    const double S = rs[0]+rs[1]+rs[2]+rs[3], SS = rss[0]+rss[1]+rss[2]+rss[3];
    const double mean = S / NELEM;
    const double var  = SS / NELEM - mean * mean;
    const float a = (float)((double)g[0] / sqrt(var + 1e-5));
    const float b = (float)((double)be[0] - mean * a);
    pout[0] = make_float2(a, b);
  }
}

// ---------------- fp32 -> fp16 conversions ----------------
__global__ __launch_bounds__(256) void act_to_half_kernel(
    const float* __restrict__ in, _Float16* __restrict__ out,
    const float2* __restrict__ param)
{
  const float a = param->x, b = param->y;
  const size_t stride = (size_t)gridDim.x * 1024;
  for (size_t i = ((size_t)blockIdx.x * 256 + threadIdx.x) * 4;
       i < (size_t)B_SZ * KDIM; i += stride) {
    const float4 v = *(const float4*)(in + i);
    f16x4 o;
    o[0] = (_Float16)elu_aff(v.x, a, b);
    o[1] = (_Float16)elu_aff(v.y, a, b);
    o[2] = (_Float16)elu_aff(v.z, a, b);
    o[3] = (_Float16)elu_aff(v.w, a, b);
    *(f16x4*)(out + i) = o;
  }
}

__global__ __launch_bounds__(256) void to_half_kernel(
    const float* __restrict__ in, _Float16* __restrict__ out, size_t n)
{
  const size_t stride = (size_t)gridDim.x * 1024;
  for (size_t i = ((size_t)blockIdx.x * 256 + threadIdx.x) * 4; i < n; i += stride) {
    const float4 v = *(const float4*)(in + i);
    f16x4 o;
    o[0] = (_Float16)v.x; o[1] = (_Float16)v.y;
    o[2] = (_Float16)v.z; o[3] = (_Float16)v.w;
    *(f16x4*)(out + i) = o;
  }
}

// ---------------- GEMM: [4096,8192]f16 x [3072,8192]^T -> fused epilogue ----
// m97 structure: 128x128 tile, BK=32, 4 waves (2x2), global_load_lds staging.
__global__ __launch_bounds__(256, 2) void gemm_f16_kernel(
    const _Float16* __restrict__ A,   // [4096][8192]
    const _Float16* __restrict__ Bm,  // [3072][8192] (= W rows)
    const float* __restrict__ blin,   // [3072]
    float* __restrict__ dout,         // u then v
    float* __restrict__ rowsq)        // [4096] accum of sum(v^2)
{
  __shared__ _Float16 sA[128 * 32];
  __shared__ _Float16 sB[128 * 32];
  const int t  = threadIdx.x;
  const int bx = blockIdx.x, by = blockIdx.y;
  const int l  = t & 63, wid = t >> 6;
  const int wr = wid >> 1, wc = wid & 1;
  const int lr = l & 15, lg = l >> 4;

  f32x4 acc[4][4];
  #pragma unroll
  for (int m = 0; m < 4; ++m)
    #pragma unroll
    for (int n = 0; n < 4; ++n)
      acc[m][n] = (f32x4){0.f, 0.f, 0.f, 0.f};

  // staging: linear tile bytes o = j*4096 + t*16 ; row = o>>6, kcol(halfs) = (o&63)>>1
  const int o0 = t * 16;
  const int r0s = o0 >> 6, kc0 = (o0 & 63) >> 1;
  const int o1 = 4096 + t * 16;
  const int r1s = o1 >> 6, kc1 = (o1 & 63) >> 1;
  const _Float16* Abase0 = A  + (size_t)(by * 128 + r0s) * KDIM + kc0;
  const _Float16* Abase1 = A  + (size_t)(by * 128 + r1s) * KDIM + kc1;
  const _Float16* Bbase0 = Bm + (size_t)(bx * 128 + r0s) * KDIM + kc0;
  const _Float16* Bbase1 = Bm + (size_t)(bx * 128 + r1s) * KDIM + kc1;
  char* sAo0 = (char*)sA + o0; char* sAo1 = (char*)sA + o1;
  char* sBo0 = (char*)sB + o0; char* sBo1 = (char*)sB + o1;

  for (int kt = 0; kt < KDIM / 32; ++kt) {
    const int k0 = kt * 32;
    gld_lds16(Abase0 + k0, sAo0);
    gld_lds16(Abase1 + k0, sAo1);
    gld_lds16(Bbase0 + k0, sBo0);
    gld_lds16(Bbase1 + k0, sBo1);
    __syncthreads();

    f16x8 af[4], bf[4];
    #pragma unroll
    for (int m = 0; m < 4; ++m)
      af[m] = *(const f16x8*)(sA + (wr * 64 + m * 16 + lr) * 32 + lg * 8);
    #pragma unroll
    for (int n = 0; n < 4; ++n)
      bf[n] = *(const f16x8*)(sB + (wc * 64 + n * 16 + lr) * 32 + lg * 8);
    #pragma unroll
    for (int m = 0; m < 4; ++m)
      #pragma unroll
      for (int n = 0; n < 4; ++n)
        acc[m][n] = __builtin_amdgcn_mfma_f32_16x16x32_f16(af[m], bf[n], acc[m][n], 0, 0, 0);
    __syncthreads();
  }

  // epilogue. C/D layout: col = lane&15, row = (lane>>4)*4 + reg
  float bias_n[4];
  #pragma unroll
  for (int n = 0; n < 4; ++n)
    bias_n[n] = blin[bx * 128 + wc * 64 + n * 16 + lr];

  const bool isv = (bx < 16);   // cols < 2048 (tile-aligned split)
  float* __restrict__ outu = dout;
  float* __restrict__ outv = dout + (size_t)B_SZ * 1024;

  #pragma unroll
  for (int m = 0; m < 4; ++m) {
    #pragma unroll
    for (int r = 0; r < 4; ++r) {
      const int row = by * 128 + wr * 64 + m * 16 + lg * 4 + r;
      float sq = 0.f;
      #pragma unroll
      for (int n = 0; n < 4; ++n) {
        const int colg = bx * 128 + wc * 64 + n * 16 + lr;
        const float val = acc[m][n][r] + bias_n[n];
        if (isv) { outv[(size_t)row * NV + colg] = val; sq += val * val; }
        else     { outu[(size_t)row * 1024 + (colg - 2048)] = val; }
      }
      if (isv) {
        sq += __shfl_xor(sq, 1, 64);
        sq += __shfl_xor(sq, 2, 64);
        sq += __shfl_xor(sq, 4, 64);
        sq += __shfl_xor(sq, 8, 64);
        if (lr == 0) atomicAdd(&rowsq[row], sq);
      }
    }
  }
}

// ---------------- v normalize ----------------
__global__ __launch_bounds__(256) void vnorm_kernel(float* __restrict__ outv,
                                                    const float* __restrict__ rowsq)
{
  const size_t i4 = (size_t)blockIdx.x * 256 + threadIdx.x;  // 4096*2048/4 total
  const int b = (int)(i4 >> 9);
  const float inv = 1.f / sqrtf(rowsq[b]);
  float4 v = ((float4*)outv)[i4];
  v.x *= inv; v.y *= inv; v.z *= inv; v.w *= inv;
  ((float4*)outv)[i4] = v;
}

// ---------------- launch ----------------
extern "C" void kernel_launch(void* const* d_in, const int* in_sizes, int n_in,
                              void* d_out, int out_size, void* d_ws, size_t ws_size,
                              hipStream_t stream)
{
  const float* x      = (const float*)d_in[0];
  const float* conv_w = (const float*)d_in[1];
  const float* conv_b = (const float*)d_in[2];
  const float* bn_g   = (const float*)d_in[3];
  const float* bn_b   = (const float*)d_in[4];
  const float* W      = (const float*)d_in[5];
  const float* blin   = (const float*)d_in[6];

  const size_t OFF_BUF1   = 134217728;                  // 128 MiB
  const size_t OFF_ROWSQ  = 268435456;                  // 256 MiB
  const size_t OFF_PART   = OFF_ROWSQ + 16384;
  const size_t OFF_PARAMS = OFF_PART + 32768;
  const size_t NEED       = OFF_PARAMS + 64;
  if (ws_size < NEED) {
    fprintf(stderr, "kernel_launch: ws_size %zu < needed %zu\n", ws_size, NEED);
    return;
  }

  char* ws = (char*)d_ws;
  float* buf[2]   = {(float*)ws, (float*)(ws + OFF_BUF1)};
  float* rowsq    = (float*)(ws + OFF_ROWSQ);
  float2* partial = (float2*)(ws + OFF_PART);
  float2* params  = (float2*)(ws + OFF_PARAMS);
  _Float16* Ah = (_Float16*)ws;                         // recycles buf0 (c6 dead)
  _Float16* Wh = (_Float16*)(ws + 67108864);            // buf0 + 64 MiB

  hipMemsetAsync(ws + OFF_ROWSQ, 0, 16384, stream);     // rowsq = 0

  conv_bn_kernel<true><<<B_SZ, 512, 0, stream>>>(
      x, buf[0], conv_w, conv_b, nullptr, partial);
  stat_reduce_kernel<<<1, 256, 0, stream>>>(partial, bn_g, bn_b, params);
  for (int i = 1; i < 8; ++i) {
    conv_bn_kernel<false><<<B_SZ, 512, 0, stream>>>(
        buf[(i + 1) & 1], buf[i & 1], conv_w + i * 9, conv_b + i,
        params + (i - 1), partial);
    stat_reduce_kernel<<<1, 256, 0, stream>>>(partial, bn_g + i, bn_b + i, params + i);
  }

  // c7 lives in buf[1]; apply BN7+ELU and quantize A; quantize W
  act_to_half_kernel<<<8192, 256, 0, stream>>>(buf[1], Ah, params + 7);
  to_half_kernel<<<6144, 256, 0, stream>>>(W, Wh, (size_t)NFEAT * KDIM);

  dim3 gg(NFEAT / 128, B_SZ / 128);
  gemm_f16_kernel<<<gg, 256, 0, stream>>>(Ah, Wh, blin, (float*)d_out, rowsq);

  vnorm_kernel<<<8192, 256, 0, stream>>>((float*)d_out + (size_t)B_SZ * 1024, rowsq);
}